// Round 1
// baseline (1146.826 us; speedup 1.0000x reference)
//
#include <hip/hip_runtime.h>
#include <math.h>

// sigmoid-form heaviside: (tanh(5x)+1)/2 == 1/(1+exp(-10x)) exactly (math identity)
__device__ __forceinline__ float hv(float x) {
    return __builtin_amdgcn_rcpf(1.0f + __expf(-10.0f * x));
}

// ---- kernel 1: per-basin MLP -> transformed params (7 planes of B) ----
__global__ void params_kernel(const float* __restrict__ attrs,
                              const float* __restrict__ w1,
                              const float* __restrict__ b1,
                              const float* __restrict__ w2,
                              const float* __restrict__ b2,
                              float* __restrict__ params, int B) {
    int b = blockIdx.x * blockDim.x + threadIdx.x;
    if (b >= B) return;
    float a[27];
#pragma unroll
    for (int i = 0; i < 27; ++i) a[i] = attrs[b * 27 + i];
    float h[32];
#pragma unroll
    for (int j = 0; j < 32; ++j) {
        float s = b1[j];
#pragma unroll
        for (int i = 0; i < 27; ++i) s = fmaf(a[i], w1[i * 32 + j], s);
        h[j] = tanhf(s);
    }
    float p[6];
#pragma unroll
    for (int k = 0; k < 6; ++k) {
        float s = b2[k];
#pragma unroll
        for (int j = 0; j < 32; ++j) s = fmaf(h[j], w2[j * 6 + k], s);
        p[k] = tanhf(s);
    }
    float tmin = (p[0] + 1.0f) * -1.5f;
    float tmax = (p[1] + 1.0f) * 1.5f;
    float ddf  = (p[2] + 1.0f) * 2.5f;
    float f    = (p[3] + 1.0f) / 20.0f;
    float smax = (p[4] + 1.0f) * 700.0f + 100.0f;
    float qmax = (p[5] + 1.0f) * 20.0f + 10.0f;
    params[0 * B + b] = tmin;
    params[1 * B + b] = tmax;
    params[2 * B + b] = ddf;
    params[3 * B + b] = f;
    params[4 * B + b] = smax;
    params[5 * B + b] = qmax;
    params[6 * B + b] = 1.0f / smax;
}

// ---- kernel 2: transpose + precompute everything (t,b)-indexed that doesn't
//      depend on state: pet, psnow, prain, Hm1=H(t-tmax), M=Hm1*ddf*(t-tmax).
//      melt = H(s0)*min(Hm1*s0, M)  (valid since Hm1>=0 distributes over min)
//      tile: 32 t x 64 b, block 256
__global__ void prep_kernel(const float* __restrict__ forcing,
                            const float* __restrict__ params,
                            float4* __restrict__ qv,
                            float* __restrict__ petT,
                            int B, int T) {
    __shared__ float lps[32][65], lpr[32][65], lhm[32][65], lM[32][65], lpe[32][65];
    int b0 = blockIdx.x * 64, t0 = blockIdx.y * 32;
    {
        int tl = threadIdx.x & 31;
        int t = t0 + tl;
        int tv = (t < T) ? t : (T - 1);
        for (int bb = threadIdx.x >> 5; bb < 64; bb += 8) {
            int b = b0 + bb;
            const float* src = forcing + ((size_t)b * T + tv) * 5;
            float p = src[0], tm = src[1], dl = src[2];
            float tmin = params[0 * B + b], tmax = params[1 * B + b], ddf = params[2 * B + b];
            float pet = 29.8f * (dl * 24.0f) * 0.611f
                        * expf(17.3f * tm / (tm + 237.3f)) / (tm + 273.2f);
            float psnow = hv(tmin - tm) * p;
            float prain = hv(tm - tmin) * p;
            float dt2 = tm - tmax;
            float Hm1 = hv(dt2);
            float M = Hm1 * (ddf * dt2);
            lps[tl][bb] = psnow;
            lpr[tl][bb] = prain;
            lhm[tl][bb] = Hm1;
            lM[tl][bb]  = M;
            lpe[tl][bb] = pet;
        }
    }
    __syncthreads();
    {
        int bl = threadIdx.x & 63;
        int b = b0 + bl;
        for (int tt = threadIdx.x >> 6; tt < 32; tt += 4) {
            int t = t0 + tt;
            if (t >= T) break;
            qv[(size_t)t * B + b] = make_float4(lps[tt][bl], lpr[tt][bl], lhm[tt][bl], lM[tt][bl]);
            petT[(size_t)t * B + b] = lpe[tt][bl];
        }
    }
}

// ---- kernel 3: the serial scan. 1 thread per basin, 8-deep prefetch ring. ----
__global__ __launch_bounds__(64, 1)
void scan_kernel(const float4* __restrict__ qv,
                 const float* __restrict__ petT,
                 const float* __restrict__ params,
                 float* __restrict__ s1T,
                 int B, int T) {
    int b = blockIdx.x * 64 + threadIdx.x;
    if (b >= B) return;
    float f    = params[3 * B + b];
    float smax = params[4 * B + b];
    float qmax = params[5 * B + b];
    float ism  = params[6 * B + b];
    float s0 = 0.0f, s1 = 0.0f;
    const int LOOK = 8;
    float4 a[LOOK];
    float pe[LOOK];
#pragma unroll
    for (int j = 0; j < LOOK; ++j) {
        int t = (j < T) ? j : 0;
        a[j]  = qv[(size_t)t * B + b];
        pe[j] = petT[(size_t)t * B + b];
    }
    for (int t0 = 0; t0 < T; t0 += LOOK) {
#pragma unroll
        for (int j = 0; j < LOOK; ++j) {
            int t = t0 + j;
            if (t >= T) break;
            float4 q = a[j];
            float pt = pe[j];
            int tn = t + LOOK;
            if (tn < T) {   // prefetch LOOK steps ahead into the same slot
                a[j]  = qv[(size_t)tn * B + b];
                pe[j] = petT[(size_t)tn * B + b];
            }
            // snow bucket: ds0 = psnow - melt, melt = H(s0)*min(Hm1*s0, M)
            float Hs0  = hv(s0);
            float melt = Hs0 * fminf(q.z * s0, q.w);
            // soil bucket
            float hs1   = hv(s1);
            float d     = s1 - smax;
            float over  = hv(d);
            float under = 1.0f - over;
            float bpe   = hs1 * pt;
            float et    = bpe * over + bpe * under * (s1 * ism);
            float ex    = __expf(f * d);            // exp(-f*(smax-s1))
            float qs    = hs1 * qmax;
            float qsub  = qs * over + qs * under * ex;
            float qsurf = hs1 * over * d;
            float ds0 = q.x - melt;
            float ds1 = q.y + melt - et - qsub - qsurf;
            s0 += fminf(fmaxf(ds0, -100000.0f), 100000.0f);
            s1 += fminf(fmaxf(ds1, -100000.0f), 100000.0f);
            s1T[(size_t)t * B + b] = s1;
        }
    }
}

// ---- kernel 4: output soilbucket (qsub+qsurf need only s1 + params, no pet)
//      + transpose (T,B) -> (B,T). tile 64x64, block 256. ----
__global__ void out_kernel(const float* __restrict__ s1T,
                           const float* __restrict__ params,
                           float* __restrict__ out,
                           int B, int T) {
    __shared__ float lq[64][65];
    int b0 = blockIdx.x * 64, t0 = blockIdx.y * 64;
    {
        int bl = threadIdx.x & 63;
        int b = b0 + bl;
        float f    = params[3 * B + b];
        float smax = params[4 * B + b];
        float qmax = params[5 * B + b];
        for (int tt = threadIdx.x >> 6; tt < 64; tt += 4) {
            int t = t0 + tt;
            int tv = (t < T) ? t : (T - 1);
            float s1 = s1T[(size_t)tv * B + b];
            float hs1   = hv(s1);
            float dd    = s1 - smax;
            float over  = hv(dd);
            float under = hv(-dd);
            float qs    = hs1 * qmax;
            float qsub  = qs * over + qs * under * __expf(f * dd);
            float qsurf = hs1 * over * dd;
            lq[tt][bl] = qsub + qsurf;
        }
    }
    __syncthreads();
    {
        int tl = threadIdx.x & 63;
        int t = t0 + tl;
        if (t < T) {
            for (int bb = threadIdx.x >> 6; bb < 64; bb += 4) {
                out[(size_t)(b0 + bb) * T + t] = lq[tl][bb];
            }
        }
    }
}

extern "C" void kernel_launch(void* const* d_in, const int* in_sizes, int n_in,
                              void* d_out, int out_size, void* d_ws, size_t ws_size,
                              hipStream_t stream) {
    const float* forcing = (const float*)d_in[0];
    const float* attrs   = (const float*)d_in[1];
    const float* w1      = (const float*)d_in[2];
    const float* b1      = (const float*)d_in[3];
    const float* w2      = (const float*)d_in[4];
    const float* b2      = (const float*)d_in[5];
    float* out = (float*)d_out;

    int B = in_sizes[1] / 27;
    int T = in_sizes[0] / (B * 5);

    char* ws = (char*)d_ws;
    size_t off = 0;
    float4* qv   = (float4*)(ws + off); off += (size_t)B * T * sizeof(float4);
    float* petT  = (float*)(ws + off);  off += (size_t)B * T * sizeof(float);
    float* s1T   = (float*)(ws + off);  off += (size_t)B * T * sizeof(float);
    float* params = (float*)(ws + off); off += (size_t)7 * B * sizeof(float);

    params_kernel<<<(B + 255) / 256, 256, 0, stream>>>(attrs, w1, b1, w2, b2, params, B);
    dim3 g2(B / 64, (T + 31) / 32);
    prep_kernel<<<g2, 256, 0, stream>>>(forcing, params, qv, petT, B, T);
    scan_kernel<<<B / 64, 64, 0, stream>>>(qv, petT, params, s1T, B, T);
    dim3 g4(B / 64, (T + 63) / 64);
    out_kernel<<<g4, 256, 0, stream>>>(s1T, params, out, B, T);
}

// Round 2
// 508.586 us; speedup vs baseline: 2.2549x; 2.2549x over previous
//
#include <hip/hip_runtime.h>
#include <math.h>

// sigmoid-form heaviside: (tanh(5x)+1)/2 == 1/(1+exp(-10x)) exactly (math identity)
__device__ __forceinline__ float hv(float x) {
    return __builtin_amdgcn_rcpf(1.0f + __expf(-10.0f * x));
}

// ---- kernel 1: per-basin MLP -> transformed params (7 planes of B) ----
__global__ void params_kernel(const float* __restrict__ attrs,
                              const float* __restrict__ w1,
                              const float* __restrict__ b1,
                              const float* __restrict__ w2,
                              const float* __restrict__ b2,
                              float* __restrict__ params, int B) {
    int b = blockIdx.x * blockDim.x + threadIdx.x;
    if (b >= B) return;
    float a[27];
#pragma unroll
    for (int i = 0; i < 27; ++i) a[i] = attrs[b * 27 + i];
    float h[32];
#pragma unroll
    for (int j = 0; j < 32; ++j) {
        float s = b1[j];
#pragma unroll
        for (int i = 0; i < 27; ++i) s = fmaf(a[i], w1[i * 32 + j], s);
        h[j] = tanhf(s);
    }
    float p[6];
#pragma unroll
    for (int k = 0; k < 6; ++k) {
        float s = b2[k];
#pragma unroll
        for (int j = 0; j < 32; ++j) s = fmaf(h[j], w2[j * 6 + k], s);
        p[k] = tanhf(s);
    }
    float tmin = (p[0] + 1.0f) * -1.5f;
    float tmax = (p[1] + 1.0f) * 1.5f;
    float ddf  = (p[2] + 1.0f) * 2.5f;
    float f    = (p[3] + 1.0f) / 20.0f;
    float smax = (p[4] + 1.0f) * 700.0f + 100.0f;
    float qmax = (p[5] + 1.0f) * 20.0f + 10.0f;
    params[0 * B + b] = tmin;
    params[1 * B + b] = tmax;
    params[2 * B + b] = ddf;
    params[3 * B + b] = f;
    params[4 * B + b] = smax;
    params[5 * B + b] = qmax;
    params[6 * B + b] = 1.0f / smax;
}

// ---- kernel 2: transpose + precompute per-(b,t) state-independent values.
//      Stage raw forcing rows (64 basins x 32 t x 5 floats = 40KB) into LDS
//      via aligned float4 (dense, coalesced), then compute & write coalesced.
//      melt = H(s0)*min(Hm1*s0, M) with Hm1=H(t-tmax), M=Hm1*ddf*(t-tmax)
//      prain = p - psnow exactly (sigma(x)+sigma(-x)=1).
__global__ __launch_bounds__(256)
void prep_kernel(const float* __restrict__ forcing,
                 const float* __restrict__ params,
                 float4* __restrict__ qv,
                 float* __restrict__ petT,
                 int B, int T) {
    __shared__ float raw[64][165];   // 160 floats/row + pad (stride 165: gcd(165,32)=1)
    int b0 = blockIdx.x * 64, t0 = blockIdx.y * 32;
    size_t total4 = ((size_t)B * T * 5) >> 2;
    // stage: 64 rows x 40 float4 each (row base dword = ((b*T)+t0)*5, %4==0 for T%4==0)
    for (int idx = threadIdx.x; idx < 64 * 40; idx += 256) {
        int row = idx / 40, quad = idx - row * 40;
        size_t f4 = ((((size_t)(b0 + row) * T + t0) * 5) >> 2) + quad;
        float4 v = make_float4(0.f, 0.f, 0.f, 0.f);
        if (f4 < total4) v = ((const float4*)forcing)[f4];
        raw[row][quad * 4 + 0] = v.x;
        raw[row][quad * 4 + 1] = v.y;
        raw[row][quad * 4 + 2] = v.z;
        raw[row][quad * 4 + 3] = v.w;
    }
    __syncthreads();
    int bl = threadIdx.x & 63;
    int b = b0 + bl;
    float tmin = params[0 * B + b], tmax = params[1 * B + b], ddf = params[2 * B + b];
    for (int tt = threadIdx.x >> 6; tt < 32; tt += 4) {
        int t = t0 + tt;
        if (t >= T) break;
        float p  = raw[bl][tt * 5 + 0];
        float tm = raw[bl][tt * 5 + 1];
        float dl = raw[bl][tt * 5 + 2];
        float pet = 29.8f * (dl * 24.0f) * 0.611f
                    * __expf(17.3f * tm / (tm + 237.3f)) / (tm + 273.2f);
        float psnow = hv(tmin - tm) * p;
        float prain = p - psnow;
        float dt2 = tm - tmax;
        float Hm1 = hv(dt2);
        float M = Hm1 * (ddf * dt2);
        qv[(size_t)t * B + b] = make_float4(psnow, prain, Hm1, M);
        petT[(size_t)t * B + b] = pet;
    }
}

// one scan step: updates s0,s1 from (q, pt) and per-basin params
#define STEP(q, pt)                                                     \
    {                                                                   \
        float Hs0  = hv(s0);                                            \
        float melt = Hs0 * fminf((q).z * s0, (q).w);                    \
        float hs1  = hv(s1);                                            \
        float d    = s1 - smax;                                         \
        float over = hv(d);                                             \
        float ex   = __expf(f * d);                                     \
        float A    = (pt) + qmax + d;                                   \
        float Bv   = fmaf((pt) * ism, s1, qmax * ex);                   \
        float loss = hs1 * fmaf(over, A - Bv, Bv);                      \
        float ds0  = (q).x - melt;                                      \
        float ds1  = (q).y + melt - loss;                               \
        s0 += fminf(fmaxf(ds0, -100000.0f), 100000.0f);                 \
        s1 += fminf(fmaxf(ds1, -100000.0f), 100000.0f);                 \
    }

// ---- kernel 3: the serial scan. 1 thread/basin, branch-free 16-deep
//      software pipeline: chunk c computes t in [c*16,(c+1)*16) while the
//      loads for chunk c+1 are in flight (issued interleaved, used 16 steps
//      = ~1500+ cycles later -> HBM latency fully covered). ----
__global__ __launch_bounds__(64, 1)
void scan_kernel(const float4* __restrict__ qv,
                 const float* __restrict__ petT,
                 const float* __restrict__ params,
                 float* __restrict__ s1T,
                 int B, int T) {
    int b = blockIdx.x * 64 + threadIdx.x;
    float f    = params[3 * B + b];
    float smax = params[4 * B + b];
    float qmax = params[5 * B + b];
    float ism  = params[6 * B + b];
    float s0 = 0.0f, s1 = 0.0f;
    constexpr int LOOK = 16;
    float4 a[LOOK];
    float pe[LOOK];
    const float4* pq = qv + b;
    const float*  pp = petT + b;
    float*        ps = s1T + b;
    const size_t strideC = (size_t)LOOK * B;
#pragma unroll
    for (int j = 0; j < LOOK; ++j) {
        a[j]  = pq[(size_t)j * B];
        pe[j] = pp[(size_t)j * B];
    }
    int nFull = T / LOOK;
    for (int c = 0; c < nFull - 1; ++c) {
#pragma unroll
        for (int j = 0; j < LOOK; ++j) {
            float4 q = a[j];
            float pt = pe[j];
            a[j]  = pq[(size_t)(j + LOOK) * B];   // prefetch chunk c+1
            pe[j] = pp[(size_t)(j + LOOK) * B];
            STEP(q, pt);
            ps[(size_t)j * B] = s1;
        }
        pq += strideC; pp += strideC; ps += strideC;
    }
    // drain chunk (no prefetch)
#pragma unroll
    for (int j = 0; j < LOOK; ++j) {
        float4 q = a[j];
        float pt = pe[j];
        STEP(q, pt);
        ps[(size_t)j * B] = s1;
    }
    pq += strideC; pp += strideC; ps += strideC;
    // tail for T % LOOK != 0
    for (int i = 0; i < T - nFull * LOOK; ++i) {
        float4 q = pq[(size_t)i * B];
        float pt = pp[(size_t)i * B];
        STEP(q, pt);
        ps[(size_t)i * B] = s1;
    }
}

// ---- kernel 4: output soilbucket (qsub+qsurf need only s1 + params, no pet)
//      + transpose (T,B) -> (B,T). tile 64x64, block 256. ----
__global__ void out_kernel(const float* __restrict__ s1T,
                           const float* __restrict__ params,
                           float* __restrict__ out,
                           int B, int T) {
    __shared__ float lq[64][65];
    int b0 = blockIdx.x * 64, t0 = blockIdx.y * 64;
    {
        int bl = threadIdx.x & 63;
        int b = b0 + bl;
        float f    = params[3 * B + b];
        float smax = params[4 * B + b];
        float qmax = params[5 * B + b];
        for (int tt = threadIdx.x >> 6; tt < 64; tt += 4) {
            int t = t0 + tt;
            int tv = (t < T) ? t : (T - 1);
            float s1 = s1T[(size_t)tv * B + b];
            float hs1   = hv(s1);
            float dd    = s1 - smax;
            float over  = hv(dd);
            float under = 1.0f - over;
            float qs    = hs1 * qmax;
            float qsub  = qs * over + qs * under * __expf(f * dd);
            float qsurf = hs1 * over * dd;
            lq[tt][bl] = qsub + qsurf;
        }
    }
    __syncthreads();
    {
        int tl = threadIdx.x & 63;
        int t = t0 + tl;
        if (t < T) {
            for (int bb = threadIdx.x >> 6; bb < 64; bb += 4) {
                out[(size_t)(b0 + bb) * T + t] = lq[tl][bb];
            }
        }
    }
}

extern "C" void kernel_launch(void* const* d_in, const int* in_sizes, int n_in,
                              void* d_out, int out_size, void* d_ws, size_t ws_size,
                              hipStream_t stream) {
    const float* forcing = (const float*)d_in[0];
    const float* attrs   = (const float*)d_in[1];
    const float* w1      = (const float*)d_in[2];
    const float* b1      = (const float*)d_in[3];
    const float* w2      = (const float*)d_in[4];
    const float* b2      = (const float*)d_in[5];
    float* out = (float*)d_out;

    int B = in_sizes[1] / 27;
    int T = in_sizes[0] / (B * 5);

    char* ws = (char*)d_ws;
    size_t off = 0;
    float4* qv   = (float4*)(ws + off); off += (size_t)B * T * sizeof(float4);
    float* petT  = (float*)(ws + off);  off += (size_t)B * T * sizeof(float);
    float* s1T   = (float*)(ws + off);  off += (size_t)B * T * sizeof(float);
    float* params = (float*)(ws + off); off += (size_t)7 * B * sizeof(float);

    params_kernel<<<(B + 255) / 256, 256, 0, stream>>>(attrs, w1, b1, w2, b2, params, B);
    dim3 g2(B / 64, (T + 31) / 32);
    prep_kernel<<<g2, 256, 0, stream>>>(forcing, params, qv, petT, B, T);
    scan_kernel<<<B / 64, 64, 0, stream>>>(qv, petT, params, s1T, B, T);
    dim3 g4(B / 64, (T + 63) / 64);
    out_kernel<<<g4, 256, 0, stream>>>(s1T, params, out, B, T);
}